// Round 9
// baseline (131.184 us; speedup 1.0000x reference)
//
#include <hip/hip_runtime.h>
#include <hip/hip_bf16.h>

#define B_ 8
#define L_ 2048
#define D_ 128
#define BL_ (B_ * L_)
#define DELTA2 0.016f   // 2*delta; delta=0.008 >= rigorous bf16 dot bound (0.004) with 2x margin
#define QCAP 4096

typedef __attribute__((ext_vector_type(8))) short bf16x8;
typedef __attribute__((ext_vector_type(4))) float f32x4;

__device__ __forceinline__ void gload_lds16(const void* g, void* l) {
    __builtin_amdgcn_global_load_lds(
        (const __attribute__((address_space(1))) unsigned int*)g,
        (__attribute__((address_space(3))) unsigned int*)l, 16, 0, 0);
}

#define WAIT_VM(N) asm volatile("s_waitcnt vmcnt(" #N ")" ::: "memory")

// ---------------- K1: normalize + bf16 cast; also zero rowmaxg/bestg ----------------
__global__ void k_norm(const float* __restrict__ ctx,
                       float* __restrict__ cn, float* __restrict__ en,
                       ushort* __restrict__ cnb, ushort* __restrict__ enb,
                       unsigned* __restrict__ rowmaxg,
                       unsigned long long* __restrict__ bestg) {
    int gtid = blockIdx.x * 256 + threadIdx.x;
    if (gtid < BL_) { rowmaxg[gtid] = 0u; bestg[gtid] = 0ULL; }

    int wid  = blockIdx.x * 4 + (threadIdx.x >> 6);   // 0..32767
    int lane = threadIdx.x & 63;
    int b   = wid >> 12;
    int rem = wid & 4095;
    int c   = rem >> 11;
    int l   = rem & 2047;

    const float* src = ctx + (size_t)wid * D_;
    float2 v = ((const float2*)src)[lane];
    float ss = v.x * v.x + v.y * v.y;
    #pragma unroll
    for (int off = 32; off; off >>= 1) ss += __shfl_down(ss, off, 64);
    ss = __shfl(ss, 0, 64);
    float n = fmaxf(sqrtf(ss), 1e-8f);
    float ox = v.x / n, oy = v.y / n;

    size_t ro = (size_t)(b * L_ + l) * D_;
    float* dst = (c == 0 ? cn : en) + ro;
    ((float2*)dst)[lane] = make_float2(ox, oy);

    __hip_bfloat16 hx = __float2bfloat16(ox), hy = __float2bfloat16(oy);
    ushort ux = *(ushort*)&hx, uy = *(ushort*)&hy;
    ushort* dstb = (c == 0 ? cnb : enb) + ro;
    ((ushort2*)dstb)[lane] = make_ushort2(ux, uy);
}

// ============ shared geometry for k_sim1/k_sim2 ============
// grid 256 = 8 batches (bid&7, XCD-local) x 8 M-blocks (256 rows) x 4 N-blocks (512 cols).
// 8 waves x 32 rows. B: 16 chunks of 32 cols (8KB); each wave stages 1KB/chunk
// (one gload_lds), all 8 waves consume via swizzled ds_read. Raw s_barrier +
// counted per-wave vmcnt (3 chunks in flight, never drained to 0 mid-loop).
// B cost: 0.5KB per output row (16x less than the 64-row/private-stream version).

#define SIM_TILE(LBUF, ACC)                                                               \
    {                                                                                     \
        _Pragma("unroll")                                                                 \
        for (int rt = 0; rt < 2; ++rt)                                                    \
            _Pragma("unroll")                                                             \
            for (int ct = 0; ct < 2; ++ct) ACC[rt][ct] = (f32x4){0.f, 0.f, 0.f, 0.f};     \
        _Pragma("unroll")                                                                 \
        for (int kc = 0; kc < 4; ++kc) {                                                  \
            int off = (kc * 64 + q * 16) ^ ((m & 7) << 4);                                \
            bf16x8 bf0 = *(const bf16x8*)(LBUF + m * 256 + off);                          \
            bf16x8 bf1 = *(const bf16x8*)(LBUF + (16 + m) * 256 + off);                   \
            _Pragma("unroll")                                                             \
            for (int rt = 0; rt < 2; ++rt) {                                              \
                ACC[rt][0] = __builtin_amdgcn_mfma_f32_16x16x32_bf16(Areg[rt*4+kc], bf0, ACC[rt][0], 0,0,0); \
                ACC[rt][1] = __builtin_amdgcn_mfma_f32_16x16x32_bf16(Areg[rt*4+kc], bf1, ACC[rt][1], 0,0,0); \
            }                                                                             \
        }                                                                                 \
    }

// ---------------- K2a: pass 1 -- global rowmax ----------------
__global__ __launch_bounds__(512, 2) void k_sim1(const ushort* __restrict__ cnb,
                                                 const ushort* __restrict__ enb,
                                                 unsigned* __restrict__ rowmaxg) {
    __shared__ __align__(16) char ring[4][8192];   // 32 KB

    const int bid = blockIdx.x;
    const int b = bid & 7, rem = bid >> 3;
    const int row0 = (rem >> 2) * 256;             // within batch
    const int col0 = (rem & 3) * 512;
    const int tid = threadIdx.x;
    const int wave = tid >> 6, lane = tid & 63;
    const int m = lane & 15, q = lane >> 4;

    const ushort* Ab = cnb + ((size_t)(b * L_) + row0 + wave * 32) * D_;
    const char*   gB = (const char*)(enb + ((size_t)(b * L_) + col0) * D_);

    bf16x8 Areg[8];
    #pragma unroll
    for (int rt = 0; rt < 2; ++rt)
        #pragma unroll
        for (int kc = 0; kc < 4; ++kc)
            Areg[rt * 4 + kc] = *(const bf16x8*)(Ab + (size_t)(rt * 16 + m) * D_ + kc * 32 + q * 8);

    auto STAGE = [&](int c) {
        int j = wave * 4 + q;                                   // col 0..31 within chunk
        const char* src = gB + (size_t)c * 8192 + j * 256 + ((m ^ (j & 7)) << 4);
        gload_lds16(src, &ring[c & 3][wave * 1024]);            // uniform base + lane*16
    };

    float runmax[8];
    #pragma unroll
    for (int s = 0; s < 8; ++s) runmax[s] = -3.0e38f;

    STAGE(0); STAGE(1); STAGE(2);
    WAIT_VM(2);                                    // Areg + chunk0 retired
    __builtin_amdgcn_s_barrier();
    #pragma unroll 1
    for (int c = 0; c < 16; ++c) {
        if (c < 13) STAGE(c + 3);
        f32x4 acc[2][2];
        const char* lbuf = ring[c & 3];
        SIM_TILE(lbuf, acc);
        #pragma unroll
        for (int rt = 0; rt < 2; ++rt)
            #pragma unroll
            for (int reg = 0; reg < 4; ++reg)
                runmax[rt * 4 + reg] = fmaxf(runmax[rt * 4 + reg],
                                             fmaxf(acc[rt][0][reg], acc[rt][1][reg]));
        if (c < 15) {
            if (c < 13)       WAIT_VM(2);          // chunk c+1 retired
            else if (c == 13) WAIT_VM(1);
            else              WAIT_VM(0);
            __builtin_amdgcn_s_barrier();
        }
    }

    #pragma unroll
    for (int s = 0; s < 8; ++s) {
        float v = runmax[s];
        v = fmaxf(v, __shfl_xor(v, 1, 64));
        v = fmaxf(v, __shfl_xor(v, 2, 64));
        v = fmaxf(v, __shfl_xor(v, 4, 64));
        v = fmaxf(v, __shfl_xor(v, 8, 64));
        runmax[s] = v;
    }
    if (m == 0) {
        #pragma unroll
        for (int rt = 0; rt < 2; ++rt)
            #pragma unroll
            for (int reg = 0; reg < 4; ++reg) {
                int grow = b * L_ + row0 + wave * 32 + rt * 16 + q * 4 + reg;
                unsigned u = __float_as_uint(runmax[rt * 4 + reg]);
                u = (u & 0x80000000u) ? ~u : (u | 0x80000000u);    // monotone f32->u32
                atomicMax(&rowmaxg[grow], u);
            }
    }
}

// ---------------- K2b: pass 2 -- recompute + capture + exact f64 repair ----------------
__global__ __launch_bounds__(512, 2) void k_sim2(const ushort* __restrict__ cnb,
                                                 const ushort* __restrict__ enb,
                                                 const float* __restrict__ cn,
                                                 const float* __restrict__ en,
                                                 const unsigned* __restrict__ rowmaxg,
                                                 unsigned long long* __restrict__ bestg) {
    __shared__ __align__(16) char ring[4][8192];   // 32 KB
    __shared__ float rowth_l[256];
    __shared__ int qbuf[QCAP];
    __shared__ int qn;

    const int bid = blockIdx.x;
    const int b = bid & 7, rem = bid >> 3;
    const int row0 = (rem >> 2) * 256;
    const int col0 = (rem & 3) * 512;
    const int tid = threadIdx.x;
    const int wave = tid >> 6, lane = tid & 63;
    const int m = lane & 15, q = lane >> 4;

    if (tid == 0) qn = 0;
    if (tid < 256) {
        unsigned u = rowmaxg[b * L_ + row0 + tid];
        float f = (u & 0x80000000u) ? __uint_as_float(u & 0x7FFFFFFFu)
                                    : __uint_as_float(~u);
        rowth_l[tid] = f - DELTA2;
    }
    __syncthreads();                                // drains all VMEM before pipeline

    float rowth_r[8];
    #pragma unroll
    for (int rt = 0; rt < 2; ++rt)
        #pragma unroll
        for (int reg = 0; reg < 4; ++reg)
            rowth_r[rt * 4 + reg] = rowth_l[wave * 32 + rt * 16 + q * 4 + reg];

    const ushort* Ab = cnb + ((size_t)(b * L_) + row0 + wave * 32) * D_;
    const char*   gB = (const char*)(enb + ((size_t)(b * L_) + col0) * D_);

    bf16x8 Areg[8];
    #pragma unroll
    for (int rt = 0; rt < 2; ++rt)
        #pragma unroll
        for (int kc = 0; kc < 4; ++kc)
            Areg[rt * 4 + kc] = *(const bf16x8*)(Ab + (size_t)(rt * 16 + m) * D_ + kc * 32 + q * 8);

    auto STAGE = [&](int c) {
        int j = wave * 4 + q;
        const char* src = gB + (size_t)c * 8192 + j * 256 + ((m ^ (j & 7)) << 4);
        gload_lds16(src, &ring[c & 3][wave * 1024]);
    };

    STAGE(0); STAGE(1); STAGE(2);
    WAIT_VM(2);
    __builtin_amdgcn_s_barrier();
    #pragma unroll 1
    for (int c = 0; c < 16; ++c) {
        if (c < 13) STAGE(c + 3);
        f32x4 acc[2][2];
        const char* lbuf = ring[c & 3];
        SIM_TILE(lbuf, acc);
        {
            #pragma unroll
            for (int rt = 0; rt < 2; ++rt)
                #pragma unroll
                for (int reg = 0; reg < 4; ++reg) {
                    float th = rowth_r[rt * 4 + reg];
                    #pragma unroll
                    for (int ct = 0; ct < 2; ++ct)
                        if (acc[rt][ct][reg] >= th) {
                            int row = wave * 32 + rt * 16 + q * 4 + reg;   // 0..255
                            int col = col0 + c * 32 + ct * 16 + m;         // 0..2047
                            int pos = atomicAdd(&qn, 1);
                            if (pos < QCAP) qbuf[pos] = (row << 12) | col;
                        }
                }
        }
        if (c < 15) {
            if (c < 13)       WAIT_VM(2);
            else if (c == 13) WAIT_VM(1);
            else              WAIT_VM(0);
            __builtin_amdgcn_s_barrier();
        }
    }
    __syncthreads();

    // exact double dots, 4 candidates/wave (16 lanes each)
    int qtot = min(qn, QCAP);
    for (int e0 = wave * 4; e0 < qtot; e0 += 32) {
        int e = e0 + q;
        bool act = (e < qtot);
        int pc = qbuf[act ? e : (qtot - 1)];
        int rl = (pc >> 12) & 255, col = pc & 0xFFF;
        const float* ar = cn + ((size_t)(b * L_) + row0 + rl) * D_;
        const float* br = en + ((size_t)(b * L_) + col) * D_;
        float4 x0 = ((const float4*)ar)[m * 2], x1 = ((const float4*)ar)[m * 2 + 1];
        float4 y0 = ((const float4*)br)[m * 2], y1 = ((const float4*)br)[m * 2 + 1];
        double s = (double)x0.x * y0.x + (double)x0.y * y0.y +
                   (double)x0.z * y0.z + (double)x0.w * y0.w +
                   (double)x1.x * y1.x + (double)x1.y * y1.y +
                   (double)x1.z * y1.z + (double)x1.w * y1.w;
        s += __shfl_xor(s, 1, 64);
        s += __shfl_xor(s, 2, 64);
        s += __shfl_xor(s, 4, 64);
        s += __shfl_xor(s, 8, 64);
        if (act && m == 0) {
            unsigned long long ub = (unsigned long long)__double_as_longlong(s);
            ub = (ub & 0x8000000000000000ULL) ? ~ub : (ub | 0x8000000000000000ULL);
            ub = (ub & ~0x7FFULL) | (unsigned long long)(2047 - col);  // tie -> lowest col
            atomicMax(&bestg[b * L_ + row0 + rl], ub);
        }
    }
}

// ---------------- K3: fused MLP + output (R8 structure; finalidx from bestg) ----------------
__global__ __launch_bounds__(512) void k_mlp(
        const float* __restrict__ cn, const float* __restrict__ en,
        const unsigned long long* __restrict__ bestg,
        const float* __restrict__ W1, const float* __restrict__ b1,
        const float* __restrict__ W2, const float* __restrict__ b2,
        float* __restrict__ out) {
    __shared__ __align__(16) float As[32][68];
    __shared__ __align__(16) float Bs[32][132];
    __shared__ float redv[2][32][16];
    __shared__ int fidxs[32];

    int tid = threadIdx.x;
    int tx = tid & 15, ty = tid >> 4;          // ty 0..31
    int rr = tid >> 3, kg = tid & 7;           // A-stage: row 0..63, kgroup 0..7
    int R0 = blockIdx.x * 32;
    int b  = R0 >> 11;
    int l0 = R0 & 2047;

    if (tid < 32) fidxs[tid] = 2047 - (int)(bestg[R0 + tid] & 0x7FFULL);

    const float* cnr = cn + ((size_t)(b * L_) + l0) * D_;
    const float* enr = en + (size_t)(b * L_) * D_;

    float acc[2][8];
    #pragma unroll
    for (int i = 0; i < 2; ++i)
        #pragma unroll
        for (int j = 0; j < 8; ++j) acc[i][j] = 0.0f;

    for (int kc = 0; kc < 4; ++kc) {
        __syncthreads();                       // covers fidxs at kc==0
        {
            const float* srow = (rr < 32) ? (cnr + (size_t)rr * D_)
                                          : (enr + (size_t)fidxs[rr - 32] * D_);
            float4 v = *(const float4*)(srow + kc * 32 + kg * 4);
            As[kg][rr]      = v.x;
            As[8 + kg][rr]  = v.y;
            As[16 + kg][rr] = v.z;
            As[24 + kg][rr] = v.w;
        }
        {
            int kr = tid >> 4;                 // 0..31
            int phys = (kr & 3) * 8 + (kr >> 2);
            const float* srcp = W1 + (size_t)(kc * 32 + kr) * D_ + tx * 8;
            *(float4*)&Bs[phys][tx * 8]     = *(const float4*)(srcp);
            *(float4*)&Bs[phys][tx * 8 + 4] = *(const float4*)(srcp + 4);
        }
        __syncthreads();
        #pragma unroll
        for (int k = 0; k < 32; ++k) {
            float a0 = As[k][ty];
            float a1 = As[k][32 + ty];
            float bb[8];
            *(float4*)&bb[0] = *(const float4*)&Bs[k][tx * 4];
            *(float4*)&bb[4] = *(const float4*)&Bs[k][64 + tx * 4];
            #pragma unroll
            for (int j = 0; j < 8; ++j) {
                acc[0][j] = fmaf(a0, bb[j], acc[0][j]);
                acc[1][j] = fmaf(a1, bb[j], acc[1][j]);
            }
        }
    }

    float w2j[8], b1j[8];
    #pragma unroll
    for (int jj = 0; jj < 8; ++jj) {
        int c = (jj < 4) ? (tx * 4 + jj) : (64 + tx * 4 + (jj - 4));
        w2j[jj] = W2[c];
        b1j[jj] = b1[c];
    }
    float bias2 = b2[0];
    __syncthreads();
    #pragma unroll
    for (int i = 0; i < 2; ++i) {
        float s = 0.0f;
        #pragma unroll
        for (int jj = 0; jj < 8; ++jj)
            s += fmaxf(acc[i][jj] + b1j[jj], 0.0f) * w2j[jj];
        redv[i][ty][tx] = s;
    }
    __syncthreads();
    if (tid < 32) {
        float s0 = 0.0f, s1 = 0.0f;
        #pragma unroll
        for (int tt = 0; tt < 16; ++tt) { s0 += redv[0][tid][tt]; s1 += redv[1][tid][tt]; }
        out[R0 + tid] = (s0 + bias2) + (s1 + bias2);
    }
}

extern "C" void kernel_launch(void* const* d_in, const int* in_sizes, int n_in,
                              void* d_out, int out_size, void* d_ws, size_t ws_size,
                              hipStream_t stream) {
    const float* context = (const float*)d_in[0];
    const float* W1 = (const float*)d_in[1];
    const float* b1 = (const float*)d_in[2];
    const float* W2 = (const float*)d_in[3];
    const float* b2 = (const float*)d_in[4];
    float* out = (float*)d_out;

    char* ws = (char*)d_ws;
    float*  cn  = (float*)(ws);                            // 8 MB
    float*  en  = (float*)(ws + 8388608);                  // 8 MB
    ushort* cnb = (ushort*)(ws + 16777216);                // 4 MB
    ushort* enb = (ushort*)(ws + 20971520);                // 4 MB
    unsigned* rowmaxg = (unsigned*)(ws + 25165824);        // 64 KB
    unsigned long long* bestg = (unsigned long long*)(ws + 25231360);  // 128 KB

    k_norm<<<8192, 256, 0, stream>>>(context, cn, en, cnb, enb, rowmaxg, bestg);
    k_sim1<<<256, 512, 0, stream>>>(cnb, enb, rowmaxg);
    k_sim2<<<256, 512, 0, stream>>>(cnb, enb, cn, en, rowmaxg, bestg);
    k_mlp<<<512, 512, 0, stream>>>(cn, en, bestg, W1, b1, W2, b2, out);
}